// Round 5
// baseline (252.543 us; speedup 1.0000x reference)
//
#include <hip/hip_runtime.h>
#include <hip/hip_bf16.h>

typedef __bf16 bf16x8 __attribute__((ext_vector_type(8)));
typedef short s16x4 __attribute__((ext_vector_type(4)));
typedef float f32x4 __attribute__((ext_vector_type(4)));
typedef unsigned short u16x8 __attribute__((ext_vector_type(8)));

#define MFMA_K32(a, b, c) __builtin_amdgcn_mfma_f32_16x16x32_bf16(a, b, c, 0, 0, 0)

// 16x16x16 bf16 MFMA; builtin exists only in device pass.
static __device__ __forceinline__ f32x4 mfma_k16(s16x4 a, s16x4 b, f32x4 c) {
#ifdef __HIP_DEVICE_COMPILE__
    return __builtin_amdgcn_mfma_f32_16x16x16bf16_1k(a, b, c, 0, 0, 0);
#else
    return c;
#endif
}

static __device__ __forceinline__ float fast_exp2(float x) {
#ifdef __HIP_DEVICE_COMPILE__
    return __builtin_amdgcn_exp2f(x);
#else
    return x;
#endif
}

// async global->LDS, 16B per lane; lds dest = wave-uniform base + lane*16
#define GLL16(gp, lp)                                              \
    __builtin_amdgcn_global_load_lds(                              \
        (const __attribute__((address_space(1))) void*)(gp),       \
        (__attribute__((address_space(3))) void*)(lp), 16, 0, 0)

// round-to-nearest-even fp32 -> bf16 (finite inputs only)
static __device__ __forceinline__ unsigned short f2bf(float f) {
    unsigned int u = __float_as_uint(f);
    u += 0x7fffu + ((u >> 16) & 1u);
    return (unsigned short)(u >> 16);
}

// packed fp32x2 -> bf16x2 (RNE) via gfx950 v_cvt_pk_bf16_f32 when available
static __device__ __forceinline__ unsigned int cvtpk_bf16(float lo, float hi) {
#if defined(__HIP_DEVICE_COMPILE__) && __has_builtin(__builtin_amdgcn_cvt_pk_bf16_f32)
    typedef __bf16 bf16x2 __attribute__((ext_vector_type(2)));
    bf16x2 r = __builtin_amdgcn_cvt_pk_bf16_f32(lo, hi);
    return __builtin_bit_cast(unsigned int, r);
#else
    return (unsigned int)f2bf(lo) | ((unsigned int)f2bf(hi) << 16);
#endif
}

#define LOG2E 1.44269504088896340736f

// ---------------------------------------------------------------------------
// Fused prep: transpose+cast w_qkv and w_out, rmsnorm x -> xn (bf16).
// bid < 3072: w_qkv tile; < 4096: w_out tile; else rmsnorm row (bid-4096).
// ---------------------------------------------------------------------------
__global__ __launch_bounds__(256) void prep_k(
    const float* __restrict__ x, const float* __restrict__ gamma,
    const float* __restrict__ w_qkv, const float* __restrict__ w_out,
    unsigned short* __restrict__ xn, unsigned short* __restrict__ wtq,
    unsigned short* __restrict__ wto) {
    __shared__ float sm[32][33];
    int bid = blockIdx.x, tid = threadIdx.x;
    if (bid < 4096) {  // transpose paths (block-uniform branch)
        const float* in;
        unsigned short* out;
        int R = 1024, C, bx, by;
        if (bid < 3072) { in = w_qkv; out = wtq; C = 3072; bx = bid % 96; by = bid / 96; }
        else { int b2 = bid - 3072; in = w_out; out = wto; C = 1024; bx = b2 % 32; by = b2 / 32; }
        int c0 = bx * 32, r0 = by * 32;
        int tr = tid >> 5, tc = tid & 31;
#pragma unroll
        for (int i = 0; i < 4; i++)
            sm[tr + i * 8][tc] = in[(size_t)(r0 + tr + i * 8) * C + c0 + tc];
        __syncthreads();
#pragma unroll
        for (int i = 0; i < 4; i++)
            out[(size_t)(c0 + tr + i * 8) * R + r0 + tc] = f2bf(sm[tc][tr + i * 8]);
    } else {  // rmsnorm
        int row = bid - 4096;
        const float* xr = x + (size_t)row * 1024;
        float4 v = *(const float4*)(xr + tid * 4);
        float ss = v.x * v.x + v.y * v.y + v.z * v.z + v.w * v.w;
#pragma unroll
        for (int off = 1; off < 64; off <<= 1) ss += __shfl_xor(ss, off, 64);
        if ((tid & 63) == 0) sm[0][tid >> 6] = ss;
        __syncthreads();
        float tot = sm[0][0] + sm[0][1] + sm[0][2] + sm[0][3];
        float f = 32.0f / fmaxf(sqrtf(tot), 1e-12f);  // sqrt(1024)=32
        float4 g = *(const float4*)(gamma + tid * 4);
        uint2 o;
        o.x = cvtpk_bf16(v.x * f * g.x, v.y * f * g.y);
        o.y = cvtpk_bf16(v.z * f * g.z, v.w * f * g.w);
        *(uint2*)(xn + (size_t)row * 1024 + tid * 4) = o;
    }
}

// ---------------------------------------------------------------------------
// GEMM (m97 structure): C[M,N] = A[M,K] * BT[N,K]^T, bf16 in, fp32 acc.
// BM x 128 tile, BK=32, global_load_lds width-16 staging into unpadded LDS.
// BM=128: 4 waves 2x2 (4x4 frags). BM=64: 4 waves 1x4 (4x2 frags).
// MODE 0: fp32 store. MODE 1: qkv epilogue (q * scale*log2e for exp2-domain
// softmax; k in [bh][n][d]; v transposed to [bh][d][n]).
// ---------------------------------------------------------------------------
template <int MODE, int BM>
__global__ __launch_bounds__(256) void gemm_bt_k(
    const unsigned short* __restrict__ A, const unsigned short* __restrict__ BT,
    float* __restrict__ C, unsigned short* __restrict__ qw,
    unsigned short* __restrict__ kw, unsigned short* __restrict__ vw,
    int M, int N, int K) {
    constexpr int RT = 4;
    constexpr int CT = (BM == 128) ? 4 : 2;
    __shared__ unsigned short As[BM][32];
    __shared__ unsigned short Bs[128][32];
    int tid = threadIdx.x;
    int wave = tid >> 6, lane = tid & 63, quad = lane >> 4, l16 = lane & 15;
    int wrb, wcb;
    if constexpr (BM == 128) { wrb = (wave >> 1) * 64; wcb = (wave & 1) * 64; }
    else { wrb = 0; wcb = wave * 32; }
    int m0 = blockIdx.y * BM, n0 = blockIdx.x * 128;
    int lrow = lane >> 2, lcol = (lane & 3) * 8;  // lane -> (row,col) in 16x32 chunk
    const unsigned short *Ag0, *Ag1 = nullptr;
    if constexpr (BM == 128) {
        Ag0 = A + (size_t)(m0 + wave * 32 + lrow) * K + lcol;
        Ag1 = A + (size_t)(m0 + wave * 32 + 16 + lrow) * K + lcol;
    } else {
        Ag0 = A + (size_t)(m0 + wave * 16 + lrow) * K + lcol;
    }
    const unsigned short* Bg0 = BT + (size_t)(n0 + wave * 32 + lrow) * K + lcol;
    const unsigned short* Bg1 = BT + (size_t)(n0 + wave * 32 + 16 + lrow) * K + lcol;
    f32x4 acc[RT][CT] = {};
    for (int k0 = 0; k0 < K; k0 += 32) {
        __syncthreads();  // prior ds_reads done before overwrite
        if constexpr (BM == 128) {
            GLL16(Ag0 + k0, &As[wave * 32][0]);
            GLL16(Ag1 + k0, &As[wave * 32 + 16][0]);
        } else {
            GLL16(Ag0 + k0, &As[wave * 16][0]);
        }
        GLL16(Bg0 + k0, &Bs[wave * 32][0]);
        GLL16(Bg1 + k0, &Bs[wave * 32 + 16][0]);
        __syncthreads();  // drains vmcnt: staging complete
        bf16x8 af[RT], bfr[CT];
#pragma unroll
        for (int t = 0; t < RT; t++)
            af[t] = *(const bf16x8*)&As[wrb + t * 16 + l16][quad * 8];
#pragma unroll
        for (int t = 0; t < CT; t++)
            bfr[t] = *(const bf16x8*)&Bs[wcb + t * 16 + l16][quad * 8];
#pragma unroll
        for (int rt = 0; rt < RT; rt++)
#pragma unroll
            for (int ct = 0; ct < CT; ct++)
                acc[rt][ct] = MFMA_K32(af[rt], bfr[ct], acc[rt][ct]);
    }
#pragma unroll
    for (int rt = 0; rt < RT; rt++) {
        int mb = m0 + wrb + rt * 16 + quad * 4;
        int b = mb >> 11, nn = mb & 2047;
#pragma unroll
        for (int ct = 0; ct < CT; ct++) {
            int col = n0 + wcb + ct * 16 + l16;
            if (MODE == 0) {
#pragma unroll
                for (int r = 0; r < 4; r++)
                    C[(size_t)(mb + r) * N + col] = acc[rt][ct][r];
            } else {
                int sec = col >> 10, ci = col & 1023;
                int hh = ci >> 6, dd = ci & 63;
                int bh = b * 16 + hh;
                if (sec == 0) {
#pragma unroll
                    for (int r = 0; r < 4; r++)
                        qw[((size_t)bh * 2048 + nn + r) * 64 + dd] =
                            f2bf(acc[rt][ct][r] * (0.125f * LOG2E));
                } else if (sec == 1) {
#pragma unroll
                    for (int r = 0; r < 4; r++)
                        kw[((size_t)bh * 2048 + nn + r) * 64 + dd] = f2bf(acc[rt][ct][r]);
                } else {
                    uint2 pk;
                    pk.x = cvtpk_bf16(acc[rt][ct][0], acc[rt][ct][1]);
                    pk.y = cvtpk_bf16(acc[rt][ct][2], acc[rt][ct][3]);
                    *(uint2*)&vw[((size_t)bh * 64 + dd) * 2048 + nn] = pk;
                }
            }
        }
    }
}

// ---------------------------------------------------------------------------
// Causal flash attention, key-split transposed form.
// Block = 64 q-rows; each wave owns a 16-KEY slice of every 64-key tile and
// ALL 64 q-rows (Q in registers). Per tile per wave LDS reads: 2 b128 (K) +
// 4 b64 (V) = 4 KB (4x less than wave-redundant form). Per-wave online
// softmax over its key slice; cross-wave (m,l,O) split-K combine once per
// phase through LDS. P stays in registers (16x16x16 PV).
// q,k: [32 bh][2048][64] bf16 (q pre-scaled by 0.125*log2e); vt: [bh][64][2048].
// o: [4096][1024] bf16 token-major. Pair (31-px, px): uniform 33 tiles/block.
// ---------------------------------------------------------------------------
__global__ __launch_bounds__(256) void attn_k(
    const unsigned short* __restrict__ q, const unsigned short* __restrict__ k,
    const unsigned short* __restrict__ vt, unsigned short* __restrict__ o) {
    __shared__ __align__(16) char smem[36864];  // K/V dbuf, overlaid by Osh at combine
    __shared__ float Msh[4][64], Lsh[4][64];
    unsigned short* KsB = (unsigned short*)smem;            // [2][64][72]
    unsigned short* VtB = (unsigned short*)(smem + 18432);  // [2][64][72]
    int bh = blockIdx.y, px = blockIdx.x;
    int tid = threadIdx.x, wave = tid >> 6, lane = tid & 63;
    int quad = lane >> 4, l16 = lane & 15;
    int b = bh >> 4, h = bh & 15;
    const unsigned short* qg = q + (size_t)bh * 2048 * 64;
    const unsigned short* kg = k + (size_t)bh * 2048 * 64;
    const unsigned short* vg = vt + (size_t)bh * 64 * 2048;
    int srow = tid >> 2, scol = (tid & 3) * 16;
    u16x8 pk0, pk1, pv0, pv1;  // prefetch registers
#pragma unroll 1
    for (int phase = 0; phase < 2; phase++) {
        int qt = phase == 0 ? (31 - px) : px;  // heavy tile first (LPT)
        int q0 = qt * 64;
        // Q fragments for all 4 n-tiles (64 q-rows), both K-halves: 32 VGPRs
        bf16x8 bq[4][2];
#pragma unroll
        for (int ct = 0; ct < 4; ct++)
#pragma unroll
            for (int ks = 0; ks < 2; ks++)
                bq[ct][ks] = *(const bf16x8*)&qg[(size_t)(q0 + ct * 16 + l16) * 64 +
                                                 ks * 32 + quad * 8];
        f32x4 ot[4][4] = {};  // [d-tile][q-tile], C-layout [d=quad*4+r][q=l16]
        float mrun[4], lrun[4];
#pragma unroll
        for (int ct = 0; ct < 4; ct++) { mrun[ct] = -1e38f; lrun[ct] = 0.f; }
        int nkt = qt + 1;
        {  // preload tile 0 into buffer 0
            const unsigned short* kp = kg + (size_t)srow * 64 + scol;
            pk0 = *(const u16x8*)kp;
            pk1 = *(const u16x8*)(kp + 8);
            const unsigned short* vp = vg + (size_t)srow * 2048 + scol;
            pv0 = *(const u16x8*)vp;
            pv1 = *(const u16x8*)(vp + 8);
            *(u16x8*)&KsB[srow * 72 + scol] = pk0;
            *(u16x8*)&KsB[srow * 72 + scol + 8] = pk1;
            *(u16x8*)&VtB[srow * 72 + scol] = pv0;
            *(u16x8*)&VtB[srow * 72 + scol + 8] = pv1;
        }
        __syncthreads();
        for (int kt = 0; kt < nkt; kt++) {
            int cb = kt & 1;
            bool pf = (kt + 1 < nkt);
            if (pf) {  // issue next tile's global loads early
                const unsigned short* kp = kg + (size_t)((kt + 1) * 64 + srow) * 64 + scol;
                pk0 = *(const u16x8*)kp;
                pk1 = *(const u16x8*)(kp + 8);
                const unsigned short* vp = vg + (size_t)srow * 2048 + (kt + 1) * 64 + scol;
                pv0 = *(const u16x8*)vp;
                pv1 = *(const u16x8*)(vp + 8);
            }
            const unsigned short* Ks = KsB + cb * 4608;
            const unsigned short* Vc = VtB + cb * 4608;
            // K slice for this wave: 16 keys x 64 d = 2 b128 reads
            bf16x8 ak0 = *(const bf16x8*)&Ks[(wave * 16 + l16) * 72 + quad * 8];
            bf16x8 ak1 = *(const bf16x8*)&Ks[(wave * 16 + l16) * 72 + 32 + quad * 8];
            // St[key=quad*4+r][q=ct*16+l16]
            f32x4 sf[4];
#pragma unroll
            for (int ct = 0; ct < 4; ct++) {
                f32x4 s = {};
                s = MFMA_K32(ak0, bq[ct][0], s);
                s = MFMA_K32(ak1, bq[ct][1], s);
                sf[ct] = s;
            }
            if (kt == qt) {  // diagonal tile: causal mask
                int keyb = wave * 16 + quad * 4;
#pragma unroll
                for (int ct = 0; ct < 4; ct++) {
                    int qloc = ct * 16 + l16;
#pragma unroll
                    for (int r = 0; r < 4; r++)
                        if (keyb + r > qloc) sf[ct][r] = -1e30f;
                }
            }
            // per-wave online softmax over this wave's 16 keys (exp2 domain)
            float al[4];
            int need = 0;
#pragma unroll
            for (int ct = 0; ct < 4; ct++) {
                float mx = fmaxf(fmaxf(sf[ct][0], sf[ct][1]),
                                 fmaxf(sf[ct][2], sf[ct][3]));
                mx = fmaxf(mx, __shfl_xor(mx, 16, 64));
                mx = fmaxf(mx, __shfl_xor(mx, 32, 64));
                float mnew = fmaxf(mrun[ct], mx);
                al[ct] = fast_exp2(mrun[ct] - mnew);
                mrun[ct] = mnew;
                float rs = 0.f;
#pragma unroll
                for (int r = 0; r < 4; r++) {
                    float p = fast_exp2(sf[ct][r] - mnew);
                    sf[ct][r] = p;
                    rs += p;
                }
                rs += __shfl_xor(rs, 16, 64);
                rs += __shfl_xor(rs, 32, 64);
                lrun[ct] = lrun[ct] * al[ct] + rs;
                need |= (al[ct] < 1.0f);
            }
            if (__any(need)) {  // skip the 64 muls when no row saw a new max
#pragma unroll
                for (int dt = 0; dt < 4; dt++)
#pragma unroll
                    for (int ct = 0; ct < 4; ct++)
#pragma unroll
                        for (int r = 0; r < 4; r++) ot[dt][ct][r] *= al[ct];
            }
            // P -> packed bf16 B-fragments (k=quad*4+j matches C-layout)
            s16x4 bpr[4];
#pragma unroll
            for (int ct = 0; ct < 4; ct++) {
                uint2 u;
                u.x = cvtpk_bf16(sf[ct][0], sf[ct][1]);
                u.y = cvtpk_bf16(sf[ct][2], sf[ct][3]);
                bpr[ct] = __builtin_bit_cast(s16x4, u);
            }
            // Ot += V^T(slice) * P^T : av reused across the 4 q-tiles
#pragma unroll
            for (int dt = 0; dt < 4; dt++) {
                s16x4 av = *(const s16x4*)&Vc[(dt * 16 + l16) * 72 + wave * 16 + quad * 4];
#pragma unroll
                for (int ct = 0; ct < 4; ct++)
                    ot[dt][ct] = mfma_k16(av, bpr[ct], ot[dt][ct]);
            }
            if (pf) {  // write prefetched tile to the other buffer
                unsigned short* Kn = KsB + (1 - cb) * 4608;
                unsigned short* Vn = VtB + (1 - cb) * 4608;
                *(u16x8*)&Kn[srow * 72 + scol] = pk0;
                *(u16x8*)&Kn[srow * 72 + scol + 8] = pk1;
                *(u16x8*)&Vn[srow * 72 + scol] = pv0;
                *(u16x8*)&Vn[srow * 72 + scol + 8] = pv1;
            }
            __syncthreads();  // single barrier per tile
        }
        // ---- split-K combine across the 4 key-slice waves ----
        if (quad == 0) {
#pragma unroll
            for (int ct = 0; ct < 4; ct++) {
                Msh[wave][ct * 16 + l16] = mrun[ct];
                Lsh[wave][ct * 16 + l16] = lrun[ct];
            }
        }
        __syncthreads();
        float fw[4];
#pragma unroll
        for (int ct = 0; ct < 4; ct++) {
            int qq = ct * 16 + l16;
            float m0 = Msh[0][qq], m1 = Msh[1][qq], m2 = Msh[2][qq], m3 = Msh[3][qq];
            float mt = fmaxf(fmaxf(m0, m1), fmaxf(m2, m3));
            float lt = fast_exp2(m0 - mt) * Lsh[0][qq] + fast_exp2(m1 - mt) * Lsh[1][qq] +
                       fast_exp2(m2 - mt) * Lsh[2][qq] + fast_exp2(m3 - mt) * Lsh[3][qq];
            fw[ct] = fast_exp2(mrun[ct] - mt) / lt;  // includes final 1/l
        }
#pragma unroll
        for (int dt = 0; dt < 4; dt++)
#pragma unroll
            for (int ct = 0; ct < 4; ct++)
#pragma unroll
                for (int r = 0; r < 4; r++) ot[dt][ct][r] *= fw[ct];
        float* OshA = (float*)smem;            // [64 q][68 d] fp32
        float* OshB = (float*)(smem + 17408);  // second region
        if (wave & 1) {  // waves 1,3 publish
            float* O = (wave == 1) ? OshA : OshB;
#pragma unroll
            for (int ct = 0; ct < 4; ct++)
#pragma unroll
                for (int dt = 0; dt < 4; dt++)
                    *(f32x4*)&O[(ct * 16 + l16) * 68 + dt * 16 + quad * 4] = ot[dt][ct];
        }
        __syncthreads();
        if (!(wave & 1)) {  // waves 0,2 accumulate partners
            float* O = (wave == 0) ? OshA : OshB;
#pragma unroll
            for (int ct = 0; ct < 4; ct++)
#pragma unroll
                for (int dt = 0; dt < 4; dt++)
                    ot[dt][ct] += *(const f32x4*)&O[(ct * 16 + l16) * 68 + dt * 16 + quad * 4];
        }
        if (wave == 2) {  // publish (2+3) sum
#pragma unroll
            for (int ct = 0; ct < 4; ct++)
#pragma unroll
                for (int dt = 0; dt < 4; dt++)
                    *(f32x4*)&OshB[(ct * 16 + l16) * 68 + dt * 16 + quad * 4] = ot[dt][ct];
        }
        __syncthreads();
        if (wave == 0) {  // final sum + store
#pragma unroll
            for (int ct = 0; ct < 4; ct++) {
#pragma unroll
                for (int dt = 0; dt < 4; dt++)
                    ot[dt][ct] += *(const f32x4*)&OshB[(ct * 16 + l16) * 68 + dt * 16 + quad * 4];
                size_t rowbase = ((size_t)b * 2048 + q0 + ct * 16 + l16) * 1024 + h * 64;
#pragma unroll
                for (int dt = 0; dt < 4; dt++) {
                    uint2 pk;
                    pk.x = cvtpk_bf16(ot[dt][ct][0], ot[dt][ct][1]);
                    pk.y = cvtpk_bf16(ot[dt][ct][2], ot[dt][ct][3]);
                    *(uint2*)&o[rowbase + dt * 16 + quad * 4] = pk;
                }
            }
        }
        __syncthreads();  // Osh regions free before next phase's preload
    }
}

extern "C" void kernel_launch(void* const* d_in, const int* in_sizes, int n_in,
                              void* d_out, int out_size, void* d_ws, size_t ws_size,
                              hipStream_t stream) {
    const float* x = (const float*)d_in[0];       // [2,2048,1024]
    const float* gamma = (const float*)d_in[1];   // [1024]
    const float* w_qkv = (const float*)d_in[2];   // [1024,3072]
    const float* w_out = (const float*)d_in[3];   // [1024,1024]
    float* out = (float*)d_out;                   // [2,2048,1024] fp32
    char* ws = (char*)d_ws;

    unsigned short* xn = (unsigned short*)(ws);              // 8 MB (reused as ao)
    unsigned short* wtq = (unsigned short*)(ws + 8388608);   // 6 MB  [3072][1024]
    unsigned short* wto = (unsigned short*)(ws + 14680064);  // 2 MB  [1024][1024]
    unsigned short* qw = (unsigned short*)(ws + 16777216);   // 8 MB  [32][2048][64]
    unsigned short* kw = (unsigned short*)(ws + 25165824);   // 8 MB  [32][2048][64]
    unsigned short* vw = (unsigned short*)(ws + 33554432);   // 8 MB  [32][64][2048]
    unsigned short* ao = xn;                                 // reuse after QKV GEMM

    prep_k<<<8192, 256, 0, stream>>>(x, gamma, w_qkv, w_out, xn, wtq, wto);
    gemm_bt_k<1, 128><<<dim3(24, 32), 256, 0, stream>>>(xn, wtq, nullptr, qw, kw, vw,
                                                        4096, 3072, 1024);
    attn_k<<<dim3(16, 32), 256, 0, stream>>>(qw, kw, vw, ao);
    gemm_bt_k<0, 64><<<dim3(8, 64), 256, 0, stream>>>(ao, wto, out, nullptr, nullptr,
                                                      nullptr, 4096, 1024, 1024);
}

// Round 6
// 246.953 us; speedup vs baseline: 1.0226x; 1.0226x over previous
//
#include <hip/hip_runtime.h>
#include <hip/hip_bf16.h>

typedef __bf16 bf16x8 __attribute__((ext_vector_type(8)));
typedef short s16x4 __attribute__((ext_vector_type(4)));
typedef float f32x4 __attribute__((ext_vector_type(4)));
typedef unsigned short u16x8 __attribute__((ext_vector_type(8)));

#define MFMA_K32(a, b, c) __builtin_amdgcn_mfma_f32_16x16x32_bf16(a, b, c, 0, 0, 0)

// 16x16x16 bf16 MFMA; builtin exists only in device pass.
static __device__ __forceinline__ f32x4 mfma_k16(s16x4 a, s16x4 b, f32x4 c) {
#ifdef __HIP_DEVICE_COMPILE__
    return __builtin_amdgcn_mfma_f32_16x16x16bf16_1k(a, b, c, 0, 0, 0);
#else
    return c;
#endif
}

static __device__ __forceinline__ float fast_exp2(float x) {
#ifdef __HIP_DEVICE_COMPILE__
    return __builtin_amdgcn_exp2f(x);
#else
    return x;
#endif
}

// async global->LDS, 16B per lane; lds dest = wave-uniform base + lane*16
#define GLL16(gp, lp)                                              \
    __builtin_amdgcn_global_load_lds(                              \
        (const __attribute__((address_space(1))) void*)(gp),       \
        (__attribute__((address_space(3))) void*)(lp), 16, 0, 0)

// round-to-nearest-even fp32 -> bf16 (finite inputs only)
static __device__ __forceinline__ unsigned short f2bf(float f) {
    unsigned int u = __float_as_uint(f);
    u += 0x7fffu + ((u >> 16) & 1u);
    return (unsigned short)(u >> 16);
}

// packed fp32x2 -> bf16x2 (RNE) via gfx950 v_cvt_pk_bf16_f32 when available
static __device__ __forceinline__ unsigned int cvtpk_bf16(float lo, float hi) {
#if defined(__HIP_DEVICE_COMPILE__) && __has_builtin(__builtin_amdgcn_cvt_pk_bf16_f32)
    typedef __bf16 bf16x2 __attribute__((ext_vector_type(2)));
    bf16x2 r = __builtin_amdgcn_cvt_pk_bf16_f32(lo, hi);
    return __builtin_bit_cast(unsigned int, r);
#else
    return (unsigned int)f2bf(lo) | ((unsigned int)f2bf(hi) << 16);
#endif
}

#define LOG2E 1.44269504088896340736f

// ---------------------------------------------------------------------------
// Fused prep: transpose+cast w_qkv and w_out, rmsnorm x -> xn (bf16).
// bid < 3072: w_qkv tile; < 4096: w_out tile; else rmsnorm row (bid-4096).
// ---------------------------------------------------------------------------
__global__ __launch_bounds__(256) void prep_k(
    const float* __restrict__ x, const float* __restrict__ gamma,
    const float* __restrict__ w_qkv, const float* __restrict__ w_out,
    unsigned short* __restrict__ xn, unsigned short* __restrict__ wtq,
    unsigned short* __restrict__ wto) {
    __shared__ float sm[32][33];
    int bid = blockIdx.x, tid = threadIdx.x;
    if (bid < 4096) {  // transpose paths (block-uniform branch)
        const float* in;
        unsigned short* out;
        int R = 1024, C, bx, by;
        if (bid < 3072) { in = w_qkv; out = wtq; C = 3072; bx = bid % 96; by = bid / 96; }
        else { int b2 = bid - 3072; in = w_out; out = wto; C = 1024; bx = b2 % 32; by = b2 / 32; }
        int c0 = bx * 32, r0 = by * 32;
        int tr = tid >> 5, tc = tid & 31;
#pragma unroll
        for (int i = 0; i < 4; i++)
            sm[tr + i * 8][tc] = in[(size_t)(r0 + tr + i * 8) * C + c0 + tc];
        __syncthreads();
#pragma unroll
        for (int i = 0; i < 4; i++)
            out[(size_t)(c0 + tr + i * 8) * R + r0 + tc] = f2bf(sm[tc][tr + i * 8]);
    } else {  // rmsnorm
        int row = bid - 4096;
        const float* xr = x + (size_t)row * 1024;
        float4 v = *(const float4*)(xr + tid * 4);
        float ss = v.x * v.x + v.y * v.y + v.z * v.z + v.w * v.w;
#pragma unroll
        for (int off = 1; off < 64; off <<= 1) ss += __shfl_xor(ss, off, 64);
        if ((tid & 63) == 0) sm[0][tid >> 6] = ss;
        __syncthreads();
        float tot = sm[0][0] + sm[0][1] + sm[0][2] + sm[0][3];
        float f = 32.0f / fmaxf(sqrtf(tot), 1e-12f);  // sqrt(1024)=32
        float4 g = *(const float4*)(gamma + tid * 4);
        uint2 o;
        o.x = cvtpk_bf16(v.x * f * g.x, v.y * f * g.y);
        o.y = cvtpk_bf16(v.z * f * g.z, v.w * f * g.w);
        *(uint2*)(xn + (size_t)row * 1024 + tid * 4) = o;
    }
}

// ---------------------------------------------------------------------------
// GEMM (m97 structure): C[M,N] = A[M,K] * BT[N,K]^T, bf16 in, fp32 acc.
// BM x 128 tile, BK=32, global_load_lds width-16 staging into unpadded LDS.
// BM=128: 4 waves 2x2 (4x4 frags). BM=64: 4 waves 1x4 (4x2 frags).
// MODE 0: fp32 store. MODE 1: qkv epilogue (q * scale*log2e for exp2-domain
// softmax; k in [bh][n][d]; v transposed to [bh][d][n]).
// ---------------------------------------------------------------------------
template <int MODE, int BM>
__global__ __launch_bounds__(256) void gemm_bt_k(
    const unsigned short* __restrict__ A, const unsigned short* __restrict__ BT,
    float* __restrict__ C, unsigned short* __restrict__ qw,
    unsigned short* __restrict__ kw, unsigned short* __restrict__ vw,
    int M, int N, int K) {
    constexpr int RT = 4;
    constexpr int CT = (BM == 128) ? 4 : 2;
    __shared__ unsigned short As[BM][32];
    __shared__ unsigned short Bs[128][32];
    int tid = threadIdx.x;
    int wave = tid >> 6, lane = tid & 63, quad = lane >> 4, l16 = lane & 15;
    int wrb, wcb;
    if constexpr (BM == 128) { wrb = (wave >> 1) * 64; wcb = (wave & 1) * 64; }
    else { wrb = 0; wcb = wave * 32; }
    int m0 = blockIdx.y * BM, n0 = blockIdx.x * 128;
    int lrow = lane >> 2, lcol = (lane & 3) * 8;  // lane -> (row,col) in 16x32 chunk
    const unsigned short *Ag0, *Ag1 = nullptr;
    if constexpr (BM == 128) {
        Ag0 = A + (size_t)(m0 + wave * 32 + lrow) * K + lcol;
        Ag1 = A + (size_t)(m0 + wave * 32 + 16 + lrow) * K + lcol;
    } else {
        Ag0 = A + (size_t)(m0 + wave * 16 + lrow) * K + lcol;
    }
    const unsigned short* Bg0 = BT + (size_t)(n0 + wave * 32 + lrow) * K + lcol;
    const unsigned short* Bg1 = BT + (size_t)(n0 + wave * 32 + 16 + lrow) * K + lcol;
    f32x4 acc[RT][CT] = {};
    for (int k0 = 0; k0 < K; k0 += 32) {
        __syncthreads();  // prior ds_reads done before overwrite
        if constexpr (BM == 128) {
            GLL16(Ag0 + k0, &As[wave * 32][0]);
            GLL16(Ag1 + k0, &As[wave * 32 + 16][0]);
        } else {
            GLL16(Ag0 + k0, &As[wave * 16][0]);
        }
        GLL16(Bg0 + k0, &Bs[wave * 32][0]);
        GLL16(Bg1 + k0, &Bs[wave * 32 + 16][0]);
        __syncthreads();  // drains vmcnt: staging complete
        bf16x8 af[RT], bfr[CT];
#pragma unroll
        for (int t = 0; t < RT; t++)
            af[t] = *(const bf16x8*)&As[wrb + t * 16 + l16][quad * 8];
#pragma unroll
        for (int t = 0; t < CT; t++)
            bfr[t] = *(const bf16x8*)&Bs[wcb + t * 16 + l16][quad * 8];
#pragma unroll
        for (int rt = 0; rt < RT; rt++)
#pragma unroll
            for (int ct = 0; ct < CT; ct++)
                acc[rt][ct] = MFMA_K32(af[rt], bfr[ct], acc[rt][ct]);
    }
#pragma unroll
    for (int rt = 0; rt < RT; rt++) {
        int mb = m0 + wrb + rt * 16 + quad * 4;
        int b = mb >> 11, nn = mb & 2047;
#pragma unroll
        for (int ct = 0; ct < CT; ct++) {
            int col = n0 + wcb + ct * 16 + l16;
            if (MODE == 0) {
#pragma unroll
                for (int r = 0; r < 4; r++)
                    C[(size_t)(mb + r) * N + col] = acc[rt][ct][r];
            } else {
                int sec = col >> 10, ci = col & 1023;
                int hh = ci >> 6, dd = ci & 63;
                int bh = b * 16 + hh;
                if (sec == 0) {
#pragma unroll
                    for (int r = 0; r < 4; r++)
                        qw[((size_t)bh * 2048 + nn + r) * 64 + dd] =
                            f2bf(acc[rt][ct][r] * (0.125f * LOG2E));
                } else if (sec == 1) {
#pragma unroll
                    for (int r = 0; r < 4; r++)
                        kw[((size_t)bh * 2048 + nn + r) * 64 + dd] = f2bf(acc[rt][ct][r]);
                } else {
                    uint2 pk;
                    pk.x = cvtpk_bf16(acc[rt][ct][0], acc[rt][ct][1]);
                    pk.y = cvtpk_bf16(acc[rt][ct][2], acc[rt][ct][3]);
                    *(uint2*)&vw[((size_t)bh * 64 + dd) * 2048 + nn] = pk;
                }
            }
        }
    }
}

// ---------------------------------------------------------------------------
// Causal flash attention — barrier-free, LDS-free, one wave per block.
// Each wave owns 32 q-rows (2 x 16-row subtiles) and sweeps its causal key
// prefix in 64-key tiles, reading K and V^T fragments DIRECTLY from global
// (K row = one 128B cache line; co-resident same-bh waves hit L1/L2).
// Transposed math: St = K*Q^T (K32 MFMA), Ot += V^T*P^T (K16 MFMA, P stays
// in registers). Zero __syncthreads, zero LDS -> waves fully independent.
// Grid (x=bh, y=chunk): XCD = linear%8 = bh%8 -> per-XCD K/V set = 4 bh
// = 2 MB < 4 MB L2. Heavy chunks (chunk = 63-y) dispatch first (LPT).
// q,k: [32 bh][2048][64] bf16 (q pre-scaled by 0.125*log2e); vt: [bh][64][2048].
// o: [4096][1024] bf16 token-major.
// ---------------------------------------------------------------------------
__global__ __launch_bounds__(64) void attn_k(
    const unsigned short* __restrict__ q, const unsigned short* __restrict__ k,
    const unsigned short* __restrict__ vt, unsigned short* __restrict__ o) {
    int bh = blockIdx.x;
    int chunk = 63 - (int)blockIdx.y;  // heavy-first LPT order
    int lane = threadIdx.x;
    int quad = lane >> 4, l16 = lane & 15;
    int b = bh >> 4, h = bh & 15;
    const unsigned short* qg = q + (size_t)bh * 2048 * 64;
    const unsigned short* kg = k + (size_t)bh * 2048 * 64;
    const unsigned short* vg = vt + (size_t)bh * 64 * 2048;
    int q0 = chunk * 32;
    // Q B-operand frags: [s][kh] rows q0+s*16+l16, d = kh*32+quad*8
    bf16x8 bq[2][2];
#pragma unroll
    for (int s = 0; s < 2; s++)
#pragma unroll
        for (int kh = 0; kh < 2; kh++)
            bq[s][kh] = *(const bf16x8*)&qg[(size_t)(q0 + s * 16 + l16) * 64 +
                                            kh * 32 + quad * 8];
    f32x4 ot[4][2] = {};  // [d-tile][s], C-layout [d=dt*16+quad*4+r][q=l16]
    float mrun[2] = {-1e38f, -1e38f}, lrun[2] = {0.f, 0.f};
    int nkt = (q0 + 31) / 64 + 1;  // causal prefix in 64-key tiles
#pragma unroll 1
    for (int kt = 0; kt < nkt; kt++) {
        // issue K loads (one full 128B line per key-row; 8 x b128)
        const unsigned short* kb = kg + (size_t)(kt * 64) * 64;
        bf16x8 ak0[4], ak1[4];
#pragma unroll
        for (int ct = 0; ct < 4; ct++) {
            const unsigned short* kr = kb + (size_t)(ct * 16 + l16) * 64;
            ak0[ct] = *(const bf16x8*)(kr + quad * 8);
            ak1[ct] = *(const bf16x8*)(kr + 32 + quad * 8);
        }
        // issue V loads early (consumed after softmax; latency covered)
        s16x4 av[4][4];
#pragma unroll
        for (int dt = 0; dt < 4; dt++) {
            const unsigned short* vr = vg + (size_t)(dt * 16 + l16) * 2048 + kt * 64;
#pragma unroll
            for (int ct = 0; ct < 4; ct++)
                av[dt][ct] = *(const s16x4*)(vr + ct * 16 + quad * 4);
        }
        // St[key=ct*16+quad*4+r][q=s*16+l16] = K . Q^T
        f32x4 sf[2][4];
#pragma unroll
        for (int s = 0; s < 2; s++)
#pragma unroll
            for (int ct = 0; ct < 4; ct++) {
                f32x4 t = {};
                t = MFMA_K32(ak0[ct], bq[s][0], t);
                t = MFMA_K32(ak1[ct], bq[s][1], t);
                sf[s][ct] = t;
            }
        if (kt == nkt - 1) {  // only the last tile straddles the diagonal
#pragma unroll
            for (int s = 0; s < 2; s++) {
                int qrow = q0 + s * 16 + l16;
#pragma unroll
                for (int ct = 0; ct < 4; ct++) {
                    int key = kt * 64 + ct * 16 + quad * 4;
#pragma unroll
                    for (int r = 0; r < 4; r++)
                        if (key + r > qrow) sf[s][ct][r] = -1e30f;
                }
            }
        }
        // per-subtile online softmax (exp2 domain), P packed to bf16 in regs
        s16x4 bpr[2][4];
        float al[2];
#pragma unroll
        for (int s = 0; s < 2; s++) {
            float mx = -1e30f;
#pragma unroll
            for (int ct = 0; ct < 4; ct++)
#pragma unroll
                for (int r = 0; r < 4; r++) mx = fmaxf(mx, sf[s][ct][r]);
            mx = fmaxf(mx, __shfl_xor(mx, 16, 64));
            mx = fmaxf(mx, __shfl_xor(mx, 32, 64));
            float mnew = fmaxf(mrun[s], mx);
            al[s] = fast_exp2(mrun[s] - mnew);
            mrun[s] = mnew;
            float rs = 0.f;
#pragma unroll
            for (int ct = 0; ct < 4; ct++)
#pragma unroll
                for (int r = 0; r < 4; r++) {
                    float p = fast_exp2(sf[s][ct][r] - mnew);
                    sf[s][ct][r] = p;
                    rs += p;
                }
            rs += __shfl_xor(rs, 16, 64);
            rs += __shfl_xor(rs, 32, 64);
            lrun[s] = lrun[s] * al[s] + rs;
#pragma unroll
            for (int ct = 0; ct < 4; ct++) {
                uint2 u;
                u.x = cvtpk_bf16(sf[s][ct][0], sf[s][ct][1]);
                u.y = cvtpk_bf16(sf[s][ct][2], sf[s][ct][3]);
                bpr[s][ct] = __builtin_bit_cast(s16x4, u);
            }
        }
        // rescale Ot, then Ot += V^T * P^T (K16; V frag shared across s)
#pragma unroll
        for (int dt = 0; dt < 4; dt++)
#pragma unroll
            for (int s = 0; s < 2; s++) {
#pragma unroll
                for (int r = 0; r < 4; r++) ot[dt][s][r] *= al[s];
#pragma unroll
                for (int ct = 0; ct < 4; ct++)
                    ot[dt][s] = mfma_k16(av[dt][ct], bpr[s][ct], ot[dt][s]);
            }
    }
    // epilogue: Ot/l -> o[(b*2048+qrow)*1024 + h*64 + d]
#pragma unroll
    for (int s = 0; s < 2; s++) {
        float inv = 1.0f / lrun[s];
        size_t rowbase = ((size_t)b * 2048 + q0 + s * 16 + l16) * 1024 + h * 64;
#pragma unroll
        for (int dt = 0; dt < 4; dt++) {
            uint2 pk;
            pk.x = cvtpk_bf16(ot[dt][s][0] * inv, ot[dt][s][1] * inv);
            pk.y = cvtpk_bf16(ot[dt][s][2] * inv, ot[dt][s][3] * inv);
            *(uint2*)&o[rowbase + dt * 16 + quad * 4] = pk;
        }
    }
}

extern "C" void kernel_launch(void* const* d_in, const int* in_sizes, int n_in,
                              void* d_out, int out_size, void* d_ws, size_t ws_size,
                              hipStream_t stream) {
    const float* x = (const float*)d_in[0];       // [2,2048,1024]
    const float* gamma = (const float*)d_in[1];   // [1024]
    const float* w_qkv = (const float*)d_in[2];   // [1024,3072]
    const float* w_out = (const float*)d_in[3];   // [1024,1024]
    float* out = (float*)d_out;                   // [2,2048,1024] fp32
    char* ws = (char*)d_ws;

    unsigned short* xn = (unsigned short*)(ws);              // 8 MB (reused as ao)
    unsigned short* wtq = (unsigned short*)(ws + 8388608);   // 6 MB  [3072][1024]
    unsigned short* wto = (unsigned short*)(ws + 14680064);  // 2 MB  [1024][1024]
    unsigned short* qw = (unsigned short*)(ws + 16777216);   // 8 MB  [32][2048][64]
    unsigned short* kw = (unsigned short*)(ws + 25165824);   // 8 MB  [32][2048][64]
    unsigned short* vw = (unsigned short*)(ws + 33554432);   // 8 MB  [32][64][2048]
    unsigned short* ao = xn;                                 // reuse after QKV GEMM

    prep_k<<<8192, 256, 0, stream>>>(x, gamma, w_qkv, w_out, xn, wtq, wto);
    gemm_bt_k<1, 128><<<dim3(24, 32), 256, 0, stream>>>(xn, wtq, nullptr, qw, kw, vw,
                                                        4096, 3072, 1024);
    attn_k<<<dim3(32, 64), 64, 0, stream>>>(qw, kw, vw, ao);
    gemm_bt_k<0, 64><<<dim3(8, 64), 256, 0, stream>>>(ao, wto, out, nullptr, nullptr,
                                                      nullptr, 4096, 1024, 1024);
}

// Round 7
// 190.830 us; speedup vs baseline: 1.3234x; 1.2941x over previous
//
#include <hip/hip_runtime.h>
#include <hip/hip_bf16.h>

typedef __bf16 bf16x8 __attribute__((ext_vector_type(8)));
typedef short s16x4 __attribute__((ext_vector_type(4)));
typedef float f32x4 __attribute__((ext_vector_type(4)));
typedef unsigned short u16x8 __attribute__((ext_vector_type(8)));

#define MFMA_K32(a, b, c) __builtin_amdgcn_mfma_f32_16x16x32_bf16(a, b, c, 0, 0, 0)

// 16x16x16 bf16 MFMA; builtin exists only in device pass.
static __device__ __forceinline__ f32x4 mfma_k16(s16x4 a, s16x4 b, f32x4 c) {
#ifdef __HIP_DEVICE_COMPILE__
    return __builtin_amdgcn_mfma_f32_16x16x16bf16_1k(a, b, c, 0, 0, 0);
#else
    return c;
#endif
}

static __device__ __forceinline__ float fast_exp2(float x) {
#ifdef __HIP_DEVICE_COMPILE__
    return __builtin_amdgcn_exp2f(x);
#else
    return x;
#endif
}

// async global->LDS, 16B per lane; lds dest = wave-uniform base + lane*16
#define GLL16(gp, lp)                                              \
    __builtin_amdgcn_global_load_lds(                              \
        (const __attribute__((address_space(1))) void*)(gp),       \
        (__attribute__((address_space(3))) void*)(lp), 16, 0, 0)

// round-to-nearest-even fp32 -> bf16 (finite inputs only)
static __device__ __forceinline__ unsigned short f2bf(float f) {
    unsigned int u = __float_as_uint(f);
    u += 0x7fffu + ((u >> 16) & 1u);
    return (unsigned short)(u >> 16);
}

// packed fp32x2 -> bf16x2 (RNE) via gfx950 v_cvt_pk_bf16_f32 when available
static __device__ __forceinline__ unsigned int cvtpk_bf16(float lo, float hi) {
#if defined(__HIP_DEVICE_COMPILE__) && __has_builtin(__builtin_amdgcn_cvt_pk_bf16_f32)
    typedef __bf16 bf16x2 __attribute__((ext_vector_type(2)));
    bf16x2 r = __builtin_amdgcn_cvt_pk_bf16_f32(lo, hi);
    return __builtin_bit_cast(unsigned int, r);
#else
    return (unsigned int)f2bf(lo) | ((unsigned int)f2bf(hi) << 16);
#endif
}

#define LOG2E 1.44269504088896340736f

// ---------------------------------------------------------------------------
// Fused prep: transpose+cast w_qkv and w_out, rmsnorm x -> xn (bf16).
// bid < 3072: w_qkv tile; < 4096: w_out tile; else rmsnorm row (bid-4096).
// ---------------------------------------------------------------------------
__global__ __launch_bounds__(256) void prep_k(
    const float* __restrict__ x, const float* __restrict__ gamma,
    const float* __restrict__ w_qkv, const float* __restrict__ w_out,
    unsigned short* __restrict__ xn, unsigned short* __restrict__ wtq,
    unsigned short* __restrict__ wto) {
    __shared__ float sm[32][33];
    int bid = blockIdx.x, tid = threadIdx.x;
    if (bid < 4096) {  // transpose paths (block-uniform branch)
        const float* in;
        unsigned short* out;
        int R = 1024, C, bx, by;
        if (bid < 3072) { in = w_qkv; out = wtq; C = 3072; bx = bid % 96; by = bid / 96; }
        else { int b2 = bid - 3072; in = w_out; out = wto; C = 1024; bx = b2 % 32; by = b2 / 32; }
        int c0 = bx * 32, r0 = by * 32;
        int tr = tid >> 5, tc = tid & 31;
#pragma unroll
        for (int i = 0; i < 4; i++)
            sm[tr + i * 8][tc] = in[(size_t)(r0 + tr + i * 8) * C + c0 + tc];
        __syncthreads();
#pragma unroll
        for (int i = 0; i < 4; i++)
            out[(size_t)(c0 + tr + i * 8) * R + r0 + tc] = f2bf(sm[tc][tr + i * 8]);
    } else {  // rmsnorm
        int row = bid - 4096;
        const float* xr = x + (size_t)row * 1024;
        float4 v = *(const float4*)(xr + tid * 4);
        float ss = v.x * v.x + v.y * v.y + v.z * v.z + v.w * v.w;
#pragma unroll
        for (int off = 1; off < 64; off <<= 1) ss += __shfl_xor(ss, off, 64);
        if ((tid & 63) == 0) sm[0][tid >> 6] = ss;
        __syncthreads();
        float tot = sm[0][0] + sm[0][1] + sm[0][2] + sm[0][3];
        float f = 32.0f / fmaxf(sqrtf(tot), 1e-12f);  // sqrt(1024)=32
        float4 g = *(const float4*)(gamma + tid * 4);
        uint2 o;
        o.x = cvtpk_bf16(v.x * f * g.x, v.y * f * g.y);
        o.y = cvtpk_bf16(v.z * f * g.z, v.w * f * g.w);
        *(uint2*)(xn + (size_t)row * 1024 + tid * 4) = o;
    }
}

// ---------------------------------------------------------------------------
// GEMM (m97 structure): C[M,N] = A[M,K] * BT[N,K]^T, bf16 in, fp32 acc.
// BM x 128 tile, BK=32, global_load_lds width-16 staging into unpadded LDS.
// BM=128: 4 waves 2x2 (4x4 frags). BM=64: 4 waves 1x4 (4x2 frags).
// MODE 0: fp32 store. MODE 1: qkv epilogue (q * scale*log2e for exp2-domain
// softmax; k in [bh][n][d]; v transposed to [bh][d][n]).
// ---------------------------------------------------------------------------
template <int MODE, int BM>
__global__ __launch_bounds__(256) void gemm_bt_k(
    const unsigned short* __restrict__ A, const unsigned short* __restrict__ BT,
    float* __restrict__ C, unsigned short* __restrict__ qw,
    unsigned short* __restrict__ kw, unsigned short* __restrict__ vw,
    int M, int N, int K) {
    constexpr int RT = 4;
    constexpr int CT = (BM == 128) ? 4 : 2;
    __shared__ unsigned short As[BM][32];
    __shared__ unsigned short Bs[128][32];
    int tid = threadIdx.x;
    int wave = tid >> 6, lane = tid & 63, quad = lane >> 4, l16 = lane & 15;
    int wrb, wcb;
    if constexpr (BM == 128) { wrb = (wave >> 1) * 64; wcb = (wave & 1) * 64; }
    else { wrb = 0; wcb = wave * 32; }
    int m0 = blockIdx.y * BM, n0 = blockIdx.x * 128;
    int lrow = lane >> 2, lcol = (lane & 3) * 8;  // lane -> (row,col) in 16x32 chunk
    const unsigned short *Ag0, *Ag1 = nullptr;
    if constexpr (BM == 128) {
        Ag0 = A + (size_t)(m0 + wave * 32 + lrow) * K + lcol;
        Ag1 = A + (size_t)(m0 + wave * 32 + 16 + lrow) * K + lcol;
    } else {
        Ag0 = A + (size_t)(m0 + wave * 16 + lrow) * K + lcol;
    }
    const unsigned short* Bg0 = BT + (size_t)(n0 + wave * 32 + lrow) * K + lcol;
    const unsigned short* Bg1 = BT + (size_t)(n0 + wave * 32 + 16 + lrow) * K + lcol;
    f32x4 acc[RT][CT] = {};
    for (int k0 = 0; k0 < K; k0 += 32) {
        __syncthreads();  // prior ds_reads done before overwrite
        if constexpr (BM == 128) {
            GLL16(Ag0 + k0, &As[wave * 32][0]);
            GLL16(Ag1 + k0, &As[wave * 32 + 16][0]);
        } else {
            GLL16(Ag0 + k0, &As[wave * 16][0]);
        }
        GLL16(Bg0 + k0, &Bs[wave * 32][0]);
        GLL16(Bg1 + k0, &Bs[wave * 32 + 16][0]);
        __syncthreads();  // drains vmcnt: staging complete
        bf16x8 af[RT], bfr[CT];
#pragma unroll
        for (int t = 0; t < RT; t++)
            af[t] = *(const bf16x8*)&As[wrb + t * 16 + l16][quad * 8];
#pragma unroll
        for (int t = 0; t < CT; t++)
            bfr[t] = *(const bf16x8*)&Bs[wcb + t * 16 + l16][quad * 8];
#pragma unroll
        for (int rt = 0; rt < RT; rt++)
#pragma unroll
            for (int ct = 0; ct < CT; ct++)
                acc[rt][ct] = MFMA_K32(af[rt], bfr[ct], acc[rt][ct]);
    }
#pragma unroll
    for (int rt = 0; rt < RT; rt++) {
        int mb = m0 + wrb + rt * 16 + quad * 4;
        int b = mb >> 11, nn = mb & 2047;
#pragma unroll
        for (int ct = 0; ct < CT; ct++) {
            int col = n0 + wcb + ct * 16 + l16;
            if (MODE == 0) {
#pragma unroll
                for (int r = 0; r < 4; r++)
                    C[(size_t)(mb + r) * N + col] = acc[rt][ct][r];
            } else {
                int sec = col >> 10, ci = col & 1023;
                int hh = ci >> 6, dd = ci & 63;
                int bh = b * 16 + hh;
                if (sec == 0) {
#pragma unroll
                    for (int r = 0; r < 4; r++)
                        qw[((size_t)bh * 2048 + nn + r) * 64 + dd] =
                            f2bf(acc[rt][ct][r] * (0.125f * LOG2E));
                } else if (sec == 1) {
#pragma unroll
                    for (int r = 0; r < 4; r++)
                        kw[((size_t)bh * 2048 + nn + r) * 64 + dd] = f2bf(acc[rt][ct][r]);
                } else {
                    uint2 pk;
                    pk.x = cvtpk_bf16(acc[rt][ct][0], acc[rt][ct][1]);
                    pk.y = cvtpk_bf16(acc[rt][ct][2], acc[rt][ct][3]);
                    *(uint2*)&vw[((size_t)bh * 64 + dd) * 2048 + nn] = pk;
                }
            }
        }
    }
}

// ---------------------------------------------------------------------------
// Causal flash attention (R4 structure, finer grid): St = K*Q^T, Ot = V^T*P^T.
// q,k: [32 bh][2048][64] bf16 (q pre-scaled by 0.125*log2e -> exp2 softmax);
// vt: [32 bh][64][2048] bf16. o: [4096][1024] bf16 token-major.
// One 64-row q-tile per block (4 waves x 16 rows); 1024 blocks -> 4
// blocks/CU (16 waves/CU) so other blocks' waves fill this block's barrier
// stalls. Grid x=bh, y->qt=31-y: heaviest 32 blocks dispatch first (LPT);
// XCD = linear%8 = bh%8 keeps per-XCD K/V set at 2 MB (< 4 MB L2).
// Double-buffered K/V LDS, register prefetch, ONE barrier per key-tile.
// P stays in registers (16x16x16 PV: C-layout k=quad*4+r = B-operand k).
// ---------------------------------------------------------------------------
__global__ __launch_bounds__(256) void attn_k(
    const unsigned short* __restrict__ q, const unsigned short* __restrict__ k,
    const unsigned short* __restrict__ vt, unsigned short* __restrict__ o) {
    __shared__ unsigned short Ks[2][64][72];  // [buf][key][d]
    __shared__ unsigned short Vt[2][64][72];  // [buf][d][key]
    int bh = blockIdx.x;
    int qt = 31 - (int)blockIdx.y;  // heavy-first LPT order
    int tid = threadIdx.x, wave = tid >> 6, lane = tid & 63;
    int quad = lane >> 4, l16 = lane & 15;
    int b = bh >> 4, h = bh & 15;
    const unsigned short* qg = q + (size_t)bh * 2048 * 64;
    const unsigned short* kg = k + (size_t)bh * 2048 * 64;
    const unsigned short* vg = vt + (size_t)bh * 64 * 2048;
    int srow = tid >> 2, scol = (tid & 3) * 16;
    u16x8 pk0, pk1, pv0, pv1;  // prefetch registers
    int q0w = qt * 64 + wave * 16;
    bf16x8 bq[2];  // Q^T B-operand: [k=d=ks*32+quad*8+j][n=qrow=l16]
#pragma unroll
    for (int ks = 0; ks < 2; ks++)
        bq[ks] = *(const bf16x8*)&qg[(size_t)(q0w + l16) * 64 + ks * 32 + quad * 8];
    f32x4 ot[4] = {};                 // Ot C-layout: [d=dt*16+quad*4+r][qrow=l16]
    float mrun = -1e38f, lrun = 0.f;  // per-lane state for qrow=q0w+l16
    int nkt = qt + 1;
    // preload tile 0
    {
        const unsigned short* kp = kg + (size_t)srow * 64 + scol;
        pk0 = *(const u16x8*)kp;
        pk1 = *(const u16x8*)(kp + 8);
        const unsigned short* vp = vg + (size_t)srow * 2048 + scol;
        pv0 = *(const u16x8*)vp;
        pv1 = *(const u16x8*)(vp + 8);
        *(u16x8*)&Ks[0][srow][scol] = pk0;
        *(u16x8*)&Ks[0][srow][scol + 8] = pk1;
        *(u16x8*)&Vt[0][srow][scol] = pv0;
        *(u16x8*)&Vt[0][srow][scol + 8] = pv1;
    }
    __syncthreads();
    for (int kt = 0; kt < nkt; kt++) {
        int cb = kt & 1;
        bool pf = (kt + 1 < nkt);
        if (pf) {  // issue next tile's global loads early (wave-uniform branch)
            const unsigned short* kp = kg + (size_t)((kt + 1) * 64 + srow) * 64 + scol;
            pk0 = *(const u16x8*)kp;
            pk1 = *(const u16x8*)(kp + 8);
            const unsigned short* vp = vg + (size_t)srow * 2048 + (kt + 1) * 64 + scol;
            pv0 = *(const u16x8*)vp;
            pv1 = *(const u16x8*)(vp + 8);
        }
        // St[key=ct*16+quad*4+r][qrow=l16] = K . Q^T
        f32x4 sf[4];
#pragma unroll
        for (int ct = 0; ct < 4; ct++) {
            bf16x8 ak0 = *(const bf16x8*)&Ks[cb][ct * 16 + l16][quad * 8];
            bf16x8 ak1 = *(const bf16x8*)&Ks[cb][ct * 16 + l16][32 + quad * 8];
            f32x4 s = {};
            s = MFMA_K32(ak0, bq[0], s);
            s = MFMA_K32(ak1, bq[1], s);
            sf[ct] = s;
        }
        if (kt == qt) {  // diagonal tile: causal mask (local indices)
            int qloc = wave * 16 + l16;
#pragma unroll
            for (int ct = 0; ct < 4; ct++)
#pragma unroll
                for (int r = 0; r < 4; r++)
                    if (ct * 16 + quad * 4 + r > qloc) sf[ct][r] = -1e30f;
        }
        // online softmax (exp2 domain; log2e pre-folded into q)
        float mx = -1e30f;
#pragma unroll
        for (int ct = 0; ct < 4; ct++)
#pragma unroll
            for (int r = 0; r < 4; r++) mx = fmaxf(mx, sf[ct][r]);
        mx = fmaxf(mx, __shfl_xor(mx, 16, 64));
        mx = fmaxf(mx, __shfl_xor(mx, 32, 64));
        float mnew = fmaxf(mrun, mx);
        float al = fast_exp2(mrun - mnew);
        mrun = mnew;
        float rs = 0.f;
#pragma unroll
        for (int ct = 0; ct < 4; ct++)
#pragma unroll
            for (int r = 0; r < 4; r++) {
                float p = fast_exp2(sf[ct][r] - mnew);
                sf[ct][r] = p;
                rs += p;
            }
        rs += __shfl_xor(rs, 16, 64);
        rs += __shfl_xor(rs, 32, 64);
        lrun = lrun * al + rs;
        // P -> packed bf16 B-fragments for 16x16x16 (k=quad*4+j = C-layout)
        s16x4 bpr[4];
#pragma unroll
        for (int ct = 0; ct < 4; ct++) {
            uint2 u;
            u.x = cvtpk_bf16(sf[ct][0], sf[ct][1]);
            u.y = cvtpk_bf16(sf[ct][2], sf[ct][3]);
            bpr[ct] = __builtin_bit_cast(s16x4, u);
        }
        // rescale Ot, then Ot += V^T * P^T
#pragma unroll
        for (int dt = 0; dt < 4; dt++) {
#pragma unroll
            for (int r = 0; r < 4; r++) ot[dt][r] *= al;
#pragma unroll
            for (int ct = 0; ct < 4; ct++) {
                s16x4 av = *(const s16x4*)&Vt[cb][dt * 16 + l16][ct * 16 + quad * 4];
                ot[dt] = mfma_k16(av, bpr[ct], ot[dt]);
            }
        }
        if (pf) {  // write prefetched tile to the other buffer
            *(u16x8*)&Ks[1 - cb][srow][scol] = pk0;
            *(u16x8*)&Ks[1 - cb][srow][scol + 8] = pk1;
            *(u16x8*)&Vt[1 - cb][srow][scol] = pv0;
            *(u16x8*)&Vt[1 - cb][srow][scol + 8] = pv1;
        }
        __syncthreads();  // single barrier per tile
    }
    // epilogue: Ot C-layout -> o[(b*2048+qrow)*1024 + h*64 + d]
    float inv = 1.0f / lrun;
    size_t rowbase = ((size_t)b * 2048 + q0w + l16) * 1024 + h * 64;
#pragma unroll
    for (int dt = 0; dt < 4; dt++) {
        uint2 pk;
        pk.x = cvtpk_bf16(ot[dt][0] * inv, ot[dt][1] * inv);
        pk.y = cvtpk_bf16(ot[dt][2] * inv, ot[dt][3] * inv);
        *(uint2*)&o[rowbase + dt * 16 + quad * 4] = pk;
    }
}

extern "C" void kernel_launch(void* const* d_in, const int* in_sizes, int n_in,
                              void* d_out, int out_size, void* d_ws, size_t ws_size,
                              hipStream_t stream) {
    const float* x = (const float*)d_in[0];       // [2,2048,1024]
    const float* gamma = (const float*)d_in[1];   // [1024]
    const float* w_qkv = (const float*)d_in[2];   // [1024,3072]
    const float* w_out = (const float*)d_in[3];   // [1024,1024]
    float* out = (float*)d_out;                   // [2,2048,1024] fp32
    char* ws = (char*)d_ws;

    unsigned short* xn = (unsigned short*)(ws);              // 8 MB (reused as ao)
    unsigned short* wtq = (unsigned short*)(ws + 8388608);   // 6 MB  [3072][1024]
    unsigned short* wto = (unsigned short*)(ws + 14680064);  // 2 MB  [1024][1024]
    unsigned short* qw = (unsigned short*)(ws + 16777216);   // 8 MB  [32][2048][64]
    unsigned short* kw = (unsigned short*)(ws + 25165824);   // 8 MB  [32][2048][64]
    unsigned short* vw = (unsigned short*)(ws + 33554432);   // 8 MB  [32][64][2048]
    unsigned short* ao = xn;                                 // reuse after QKV GEMM

    prep_k<<<8192, 256, 0, stream>>>(x, gamma, w_qkv, w_out, xn, wtq, wto);
    gemm_bt_k<1, 128><<<dim3(24, 32), 256, 0, stream>>>(xn, wtq, nullptr, qw, kw, vw,
                                                        4096, 3072, 1024);
    attn_k<<<dim3(32, 32), 256, 0, stream>>>(qw, kw, vw, ao);
    gemm_bt_k<0, 64><<<dim3(8, 64), 256, 0, stream>>>(ao, wto, out, nullptr, nullptr,
                                                      nullptr, 4096, 1024, 1024);
}